// Round 8
// baseline (1384.331 us; speedup 1.0000x reference)
//
#include <hip/hip_runtime.h>
#include <math.h>

#define NB   2048   // batch
#define NSEQ 65     // sequence incl. origin
#define ND   256    // IN_DIM (K)
#define NH   8      // heads
#define NL   256    // L
#define NS   64     // walk length (S-1)
#define APAD 264    // padded A row (aux kernels only)
#define AROW 288    // attn A-tile row stride: 576B, rows alternate bank base 0/16
#define LOG2E 1.44269504088896f
#define INV2PI 0.15915494309189535f

typedef _Float16 f16;
typedef _Float16 f16x4 __attribute__((ext_vector_type(4)));
typedef _Float16 f16x8 __attribute__((ext_vector_type(8)));
typedef float    f32x4 __attribute__((ext_vector_type(4)));

// sigmoid with log2e pre-folded into the argument: 1/(1+2^-x)
__device__ __forceinline__ float sigmoid2_(float x) {
    float e;
    asm("v_exp_f32 %0, -%1" : "=v"(e) : "v"(x));
    return __builtin_amdgcn_rcpf(1.0f + e);
}
// cos for arguments known to be in (-2pi, 2pi): raw v_cos on revolutions
__device__ __forceinline__ float cos_small_(float x) {
    float r;
    asm("v_cos_f32 %0, %1" : "=v"(r) : "v"(x * INV2PI));
    return r;
}

// ---------------------------------------------------------------------------
// Prep: Wq/Wv/Wk (H,K,N) f32 -> wh[(h*3+m)][n][k] f16 (k contiguous), m=q,v,k
// All three scaled by LOG2E: their GEMM outputs feed sigmoids only.
// ---------------------------------------------------------------------------
__global__ __launch_bounds__(256) void wh_kernel(const float* __restrict__ Wq,
                                                 const float* __restrict__ Wv,
                                                 const float* __restrict__ Wk,
                                                 f16* __restrict__ wh) {
    int hm = blockIdx.x >> 4;            // h*3+m, 24 values
    int h  = hm / 3, m = hm % 3;
    int n  = ((blockIdx.x & 15) << 4) + (threadIdx.x >> 4);
    int kc = (threadIdx.x & 15) << 4;
    const float* src = (m == 0 ? Wq : (m == 1 ? Wv : Wk)) + h * (ND * NL);
    f16x8 t0, t1;
    #pragma unroll
    for (int j = 0; j < 8; ++j) t0[j] = (f16)(src[(kc + j) * NL + n] * LOG2E);
    #pragma unroll
    for (int j = 0; j < 8; ++j) t1[j] = (f16)(src[(kc + 8 + j) * NL + n] * LOG2E);
    f16* dst = wh + ((size_t)(hm * 256 + n)) * 256 + kc;
    *(f16x8*)dst       = t0;
    *(f16x8*)(dst + 8) = t1;
}

// ---------------------------------------------------------------------------
// Prep: O (2048,256) f32 -> OT[n][k] f16 (k contiguous), scaled by LOG2E
// ---------------------------------------------------------------------------
__global__ __launch_bounds__(256) void ot_kernel(const float* __restrict__ O,
                                                 f16* __restrict__ OT) {
    int n = blockIdx.x;
    int t = threadIdx.x;
    f16x8 v;
    #pragma unroll
    for (int j = 0; j < 8; ++j) v[j] = (f16)(O[(size_t)(t * 8 + j) * 256 + n] * LOG2E);
    *(f16x8*)(OT + (size_t)n * 2048 + t * 8) = v;
}

// ---------------------------------------------------------------------------
// PKT[h][l][s] = LOG2E * P[s]·Wk[h][:,l]  (transposed; feeds k-sigmoid only)
// ---------------------------------------------------------------------------
__global__ __launch_bounds__(256) void pkt_kernel(const float* __restrict__ P,
                                                  const float* __restrict__ Wk,
                                                  float* __restrict__ PKT) {
    int h = blockIdx.x >> 6;
    int s = blockIdx.x & 63;
    int t = threadIdx.x;
    __shared__ float p_s[ND];
    p_s[t] = P[s * ND + t];
    __syncthreads();
    const float* wk = Wk + h * (ND * NL) + t;
    float acc = 0.f;
    #pragma unroll 8
    for (int d = 0; d < ND; ++d) acc = fmaf(p_s[d], wk[d * NL], acc);
    PKT[((size_t)h * NL + t) * NS + s] = acc * LOG2E;
}

// ---------------------------------------------------------------------------
// OK[h][b][l] = origin_b · (LOG2E*Wk[h][:,l])  as f16 MFMA GEMM
// ---------------------------------------------------------------------------
__global__ __launch_bounds__(256) void ok_gemm(const float* __restrict__ x,
                                               const f16*   __restrict__ wh,
                                               float* __restrict__ OK) {
    int mblk = blockIdx.x >> 4;          // 32
    int nblk = blockIdx.x & 15;          // 16
    int b0 = mblk * 64;
    int h  = nblk >> 1;
    int l0 = (nblk & 1) * 128;
    int t = threadIdx.x;
    int w = t >> 6, lane = t & 63, c = lane & 15, g = lane >> 4;

    __shared__ f16 Ao[64 * APAD];
    #pragma unroll
    for (int it = 0; it < 16; ++it) {
        int idx4 = it * 256 + t;
        int s = idx4 >> 6, kq = idx4 & 63;
        float4 v = *(const float4*)(x + (size_t)(b0 + s) * (NSEQ * ND) + kq * 4);
        *(f16x4*)(&Ao[s * APAD + kq * 4]) = (f16x4){(f16)v.x, (f16)v.y, (f16)v.z, (f16)v.w};
    }
    __syncthreads();

    f32x4 acc[4][2];
    #pragma unroll
    for (int mt = 0; mt < 4; ++mt)
        #pragma unroll
        for (int nt = 0; nt < 2; ++nt) acc[mt][nt] = (f32x4){0.f, 0.f, 0.f, 0.f};

    const f16* bb = wh + ((size_t)((h * 3 + 2) * 256 + l0 + w * 32 + c)) * 256;
    #pragma unroll 2
    for (int kk = 0; kk < 8; ++kk) {
        int k0 = kk * 32 + g * 8;
        f16x8 af[4];
        #pragma unroll
        for (int mt = 0; mt < 4; ++mt)
            af[mt] = *(const f16x8*)(&Ao[(mt * 16 + c) * APAD + k0]);
        #pragma unroll
        for (int nt = 0; nt < 2; ++nt) {
            f16x8 bf = *(const f16x8*)(bb + nt * 16 * 256 + k0);
            #pragma unroll
            for (int mt = 0; mt < 4; ++mt)
                acc[mt][nt] = __builtin_amdgcn_mfma_f32_16x16x32_f16(af[mt], bf, acc[mt][nt], 0, 0, 0);
        }
    }
    #pragma unroll
    for (int mt = 0; mt < 4; ++mt)
        #pragma unroll
        for (int nt = 0; nt < 2; ++nt)
            #pragma unroll
            for (int r = 0; r < 4; ++r)
                OK[((size_t)h * NB + b0 + mt * 16 + g * 4 + r) * NL + l0 + w * 32 + nt * 16 + c]
                    = acc[mt][nt][r];
}

// ---------------------------------------------------------------------------
// Main fused kernel: one block/batch; 512 threads = 8 waves, one head/wave.
// R5 base (passed, 681us, VGPR 48 / cap 85, no spill, 46.7% occ). Occupancy
// is pinned by the unified register footprint (session table: 48->47%,
// 36->67%, 32->89%; no-spill minimum for this algorithm > 40), so this
// version attacks PER-WAVE latency instead, via semantics-safe changes only:
//  1. kk loop FULLY unrolled (was 2): all 32 LDS reads + 16 bf loads in one
//     scheduling window -> deeper load-ahead using the 37 spare regs.
//  2. AROW=288 (576B row stride; proven correct in R3): row parity alternates
//     bank base 0/16, breaking the 8-bank-group aliasing that costs exactly
//     4.0 conflict-cycles per ds_read_b128 at AROW=256.
//  3. s_setprio(1) around MFMA clusters (waves run barrier-free + rotated:
//     the independent-wave regime where setprio measured +4-7%).
// ---------------------------------------------------------------------------
__global__ __launch_bounds__(512, 3) void attn_mfma(
        const float* __restrict__ x,
        const f16*   __restrict__ wh,
        const float* __restrict__ W,
        const float* __restrict__ PKT,
        const float* __restrict__ OK,
        f16* __restrict__ res) {
    int b = blockIdx.x;
    int t = threadIdx.x;
    int w    = t >> 6;                   // 0..7 = head
    int lane = t & 63;
    int c = lane & 15;
    int g = lane >> 4;

    __shared__ f16 A[NS * AROW];         // 36864 B, swizzled + padded layout

    const float* xb = x + (size_t)b * (NSEQ * ND);

    // --- stage A (walk) once, swizzled ------------------------------------
    #pragma unroll
    for (int it = 0; it < 8; ++it) {
        int idx4 = it * 512 + t;
        int s  = idx4 >> 6;
        int kq = idx4 & 63;
        float4 v = *(const float4*)(xb + (1 + s) * ND + kq * 4);
        int kp = (kq * 4) ^ ((s & 7) << 3);
        *(f16x4*)(&A[s * AROW + kp]) = (f16x4){(f16)v.x, (f16)v.y, (f16)v.z, (f16)v.w};
    }
    __syncthreads();

    int swz = (c & 7) << 3;              // read-side swizzle (row&7 == c&7)
    int rot = b & 7;                     // chunk-phase rotation
    int h = w;                           // wave-private head

    // ---- pass 1: q-GEMM + edge, 8 chunks of 32 l-cols --------------------
    float part[4][4];                    // [mt][r] -> s = mt*16 + g*4 + r
    #pragma unroll
    for (int mt = 0; mt < 4; ++mt)
        #pragma unroll
        for (int r = 0; r < 4; ++r) part[mt][r] = 0.f;

    for (int ci = 0; ci < 8; ++ci) {
        int ch = (ci + rot) & 7;
        f32x4 acc[4][2];
        #pragma unroll
        for (int mt = 0; mt < 4; ++mt)
            #pragma unroll
            for (int nt = 0; nt < 2; ++nt) acc[mt][nt] = (f32x4){0.f, 0.f, 0.f, 0.f};

        const f16* bq = wh + ((size_t)((h * 3 + 0) * 256 + ch * 32 + c)) * 256;
        __builtin_amdgcn_s_setprio(1);
        #pragma unroll
        for (int kk = 0; kk < 8; ++kk) {
            int k0 = kk * 32 + g * 8;
            f16x8 af[4];
            #pragma unroll
            for (int mt = 0; mt < 4; ++mt)
                af[mt] = *(const f16x8*)(&A[(mt * 16 + c) * AROW + (k0 ^ swz)]);
            #pragma unroll
            for (int nt = 0; nt < 2; ++nt) {
                f16x8 bf = *(const f16x8*)(bq + nt * 16 * 256 + k0);
                #pragma unroll
                for (int mt = 0; mt < 4; ++mt)
                    acc[mt][nt] = __builtin_amdgcn_mfma_f32_16x16x32_f16(af[mt], bf, acc[mt][nt], 0, 0, 0);
            }
        }
        __builtin_amdgcn_s_setprio(0);
        // edge for this chunk (bias omitted: softmax-invariant shift)
        #pragma unroll
        for (int nt = 0; nt < 2; ++nt) {
            int l = ch * 32 + nt * 16 + c;
            float wl  = W[h * NL + l];
            float okv = OK[((size_t)h * NB + b) * NL + l];
            const float* pkcol = PKT + ((size_t)h * NL + l) * NS + g * 4;
            #pragma unroll
            for (int mt = 0; mt < 4; ++mt) {
                float4 pk4 = *(const float4*)(pkcol + mt * 16);
                float pks[4] = {pk4.x, pk4.y, pk4.z, pk4.w};
                #pragma unroll
                for (int r = 0; r < 4; ++r) {
                    float qs = sigmoid2_(acc[mt][nt][r]);
                    float ks = sigmoid2_(okv + pks[r]);
                    part[mt][r] = fmaf(cos_small_(ks * qs), wl, part[mt][r]);
                }
            }
        }
    }

    // ---- in-wave score reduction over c, then softmax over 64 s ----------
    #pragma unroll
    for (int mt = 0; mt < 4; ++mt)
        #pragma unroll
        for (int r = 0; r < 4; ++r) {
            float v = part[mt][r];
            v += __shfl_xor(v, 1, 64);
            v += __shfl_xor(v, 2, 64);
            v += __shfl_xor(v, 4, 64);
            v += __shfl_xor(v, 8, 64);
            part[mt][r] = v;             // score[s], uniform over c
        }
    float m = part[0][0];
    #pragma unroll
    for (int mt = 0; mt < 4; ++mt)
        #pragma unroll
        for (int r = 0; r < 4; ++r) m = fmaxf(m, part[mt][r]);
    m = fmaxf(m, __shfl_xor(m, 16, 64));
    m = fmaxf(m, __shfl_xor(m, 32, 64));
    float ssum = 0.f;
    #pragma unroll
    for (int mt = 0; mt < 4; ++mt)
        #pragma unroll
        for (int r = 0; r < 4; ++r) {
            float e = __expf(part[mt][r] - m);
            part[mt][r] = e;
            ssum += e;
        }
    ssum += __shfl_xor(ssum, 16, 64);
    ssum += __shfl_xor(ssum, 32, 64);
    float rinv = __builtin_amdgcn_rcpf(ssum);
    #pragma unroll
    for (int mt = 0; mt < 4; ++mt)
        #pragma unroll
        for (int r = 0; r < 4; ++r) part[mt][r] *= rinv;   // p_s

    // ---- pass 2: v-GEMM + weighted sigmoid sum, 8 chunks -----------------
    for (int ci = 0; ci < 8; ++ci) {
        int ch = (ci + rot) & 7;
        f32x4 acc[4][2];
        #pragma unroll
        for (int mt = 0; mt < 4; ++mt)
            #pragma unroll
            for (int nt = 0; nt < 2; ++nt) acc[mt][nt] = (f32x4){0.f, 0.f, 0.f, 0.f};

        const f16* bv = wh + ((size_t)((h * 3 + 1) * 256 + ch * 32 + c)) * 256;
        __builtin_amdgcn_s_setprio(1);
        #pragma unroll
        for (int kk = 0; kk < 8; ++kk) {
            int k0 = kk * 32 + g * 8;
            f16x8 af[4];
            #pragma unroll
            for (int mt = 0; mt < 4; ++mt)
                af[mt] = *(const f16x8*)(&A[(mt * 16 + c) * AROW + (k0 ^ swz)]);
            #pragma unroll
            for (int nt = 0; nt < 2; ++nt) {
                f16x8 bf = *(const f16x8*)(bv + nt * 16 * 256 + k0);
                #pragma unroll
                for (int mt = 0; mt < 4; ++mt)
                    acc[mt][nt] = __builtin_amdgcn_mfma_f32_16x16x32_f16(af[mt], bf, acc[mt][nt], 0, 0, 0);
            }
        }
        __builtin_amdgcn_s_setprio(0);
        #pragma unroll
        for (int nt = 0; nt < 2; ++nt) {
            float v = 0.f;
            #pragma unroll
            for (int mt = 0; mt < 4; ++mt)
                #pragma unroll
                for (int r = 0; r < 4; ++r)
                    v = fmaf(part[mt][r], sigmoid2_(acc[mt][nt][r]), v);
            v += __shfl_xor(v, 16, 64);
            v += __shfl_xor(v, 32, 64);
            if (g == 0)
                res[(size_t)b * 2048 + h * NL + ch * 32 + nt * 16 + c] = (f16)v;
        }
    }
}

// ---------------------------------------------------------------------------
// out GEMM: out[b][0:256] = sigmoid(res[b] @ O)  (f16 MFMA, K=2048)
// 32-row M tiles -> 128 blocks; OT pre-scaled by LOG2E -> sigmoid2_ epilogue
// ---------------------------------------------------------------------------
__global__ __launch_bounds__(256) void out_gemm(
        const float* __restrict__ x,
        const f16*   __restrict__ res,
        const f16*   __restrict__ OT,
        float* __restrict__ out) {
    int mblk = blockIdx.x >> 1;          // 64 tiles of 32 rows
    int nblk = blockIdx.x & 1;           // 128 cols each
    int b0 = mblk * 32;
    int t  = threadIdx.x;
    int w    = t >> 6;
    int lane = t & 63;
    int c = lane & 15;
    int g = lane >> 4;

    __shared__ f16 Ao[32 * APAD];

    f32x4 acc[2][2];
    #pragma unroll
    for (int mt = 0; mt < 2; ++mt)
        #pragma unroll
        for (int nt = 0; nt < 2; ++nt) acc[mt][nt] = (f32x4){0.f, 0.f, 0.f, 0.f};

    for (int chunk = 0; chunk < 8; ++chunk) {
        int kbase = chunk * 256;
        __syncthreads();
        #pragma unroll
        for (int it = 0; it < 4; ++it) {
            int id  = it * 256 + t;
            int row = id >> 5;
            int kc  = (id & 31) << 3;
            *(f16x8*)(&Ao[row * APAD + kc]) =
                *(const f16x8*)(res + (size_t)(b0 + row) * 2048 + kbase + kc);
        }
        __syncthreads();
        #pragma unroll
        for (int kk = 0; kk < 8; ++kk) {
            int k0 = kk * 32 + g * 8;
            f16x8 af[2];
            #pragma unroll
            for (int mt = 0; mt < 2; ++mt)
                af[mt] = *(const f16x8*)(&Ao[(mt * 16 + c) * APAD + k0]);
            #pragma unroll
            for (int nt = 0; nt < 2; ++nt) {
                f16x8 bf = *(const f16x8*)(OT + (size_t)(nblk * 128 + w * 32 + nt * 16 + c) * 2048 + kbase + k0);
                #pragma unroll
                for (int mt = 0; mt < 2; ++mt)
                    acc[mt][nt] = __builtin_amdgcn_mfma_f32_16x16x32_f16(af[mt], bf, acc[mt][nt], 0, 0, 0);
            }
        }
    }
    #pragma unroll
    for (int mt = 0; mt < 2; ++mt)
        #pragma unroll
        for (int nt = 0; nt < 2; ++nt)
            #pragma unroll
            for (int r = 0; r < 4; ++r) {
                int row = mt * 16 + g * 4 + r;
                int col = nblk * 128 + w * 32 + nt * 16 + c;
                out[(size_t)(b0 + row) * 512 + col] = sigmoid2_(acc[mt][nt][r]);
            }
    if (nblk == 1) {                     // origin passthrough for these 32 rows
        for (int r2 = 0; r2 < 32; ++r2)
            out[(size_t)(b0 + r2) * 512 + 256 + t] = x[(size_t)(b0 + r2) * (NSEQ * ND) + t];
    }
}

// ---------------------------------------------------------------------------
extern "C" void kernel_launch(void* const* d_in, const int* in_sizes, int n_in,
                              void* d_out, int out_size, void* d_ws, size_t ws_size,
                              hipStream_t stream) {
    const float* x    = (const float*)d_in[0];
    const float* Wq   = (const float*)d_in[1];
    const float* Wk   = (const float*)d_in[2];
    const float* Wv   = (const float*)d_in[3];
    const float* W    = (const float*)d_in[4];
    const float* O    = (const float*)d_in[5];
    const float* P    = (const float*)d_in[6];
    // d_in[7] = bias: unused — softmax is invariant to the bias*sum(W) shift
    float* out = (float*)d_out;

    // ws carve: wh 3MB | OT 1MB | PKT 512KB | OK 16MB | res 8MB  (~28.5MB)
    char* wsb = (char*)d_ws;
    f16*   wh  = (f16*)wsb;                       // 3*8*256*256 f16 = 3145728 B
    f16*   OT  = (f16*)(wsb + 3145728);           // 256*2048 f16   = 1048576 B
    float* PKT = (float*)(wsb + 4194304);         // 8*256*64 f32   = 524288 B
    float* OK  = (float*)(wsb + 4718592);         // 8*2048*256 f32 = 16777216 B
    f16*   res = (f16*)(wsb + 21495808);          // 2048*2048 f16  = 8388608 B

    wh_kernel<<<384, 256, 0, stream>>>(Wq, Wv, Wk, wh);
    ot_kernel<<<256, 256, 0, stream>>>(O, OT);
    pkt_kernel<<<NH * NS, 256, 0, stream>>>(P, Wk, PKT);
    ok_gemm<<<512, 256, 0, stream>>>(x, wh, OK);
    attn_mfma<<<NB, 512, 0, stream>>>(x, wh, W, PKT, OK, res);
    out_gemm<<<128, 256, 0, stream>>>(x, res, OT, out);
}

// Round 9
// 814.511 us; speedup vs baseline: 1.6996x; 1.6996x over previous
//
#include <hip/hip_runtime.h>
#include <math.h>

#define NB   2048   // batch
#define NSEQ 65     // sequence incl. origin
#define ND   256    // IN_DIM (K)
#define NH   8      // heads
#define NL   256    // L
#define NS   64     // walk length (S-1)
#define APAD 264    // padded A row (aux kernels only)
#define AROW 288    // attn A-tile row stride: 576B; with the swizzle this cut
                    // measured conflicts 33.55M -> 4.19M (R8)
#define LOG2E 1.44269504088896f
#define INV2PI 0.15915494309189535f

typedef _Float16 f16;
typedef _Float16 f16x4 __attribute__((ext_vector_type(4)));
typedef _Float16 f16x8 __attribute__((ext_vector_type(8)));
typedef float    f32x4 __attribute__((ext_vector_type(4)));

// sigmoid with log2e pre-folded into the argument: 1/(1+2^-x)
__device__ __forceinline__ float sigmoid2_(float x) {
    float e;
    asm("v_exp_f32 %0, -%1" : "=v"(e) : "v"(x));
    return __builtin_amdgcn_rcpf(1.0f + e);
}
// cos for arguments known to be in (-2pi, 2pi): raw v_cos on revolutions
__device__ __forceinline__ float cos_small_(float x) {
    float r;
    asm("v_cos_f32 %0, %1" : "=v"(r) : "v"(x * INV2PI));
    return r;
}

// ---------------------------------------------------------------------------
// Prep: Wq/Wv/Wk (H,K,N) f32 -> wh[(h*3+m)][n][k] f16 (k contiguous), m=q,v,k
// All three scaled by LOG2E: their GEMM outputs feed sigmoids only.
// ---------------------------------------------------------------------------
__global__ __launch_bounds__(256) void wh_kernel(const float* __restrict__ Wq,
                                                 const float* __restrict__ Wv,
                                                 const float* __restrict__ Wk,
                                                 f16* __restrict__ wh) {
    int hm = blockIdx.x >> 4;            // h*3+m, 24 values
    int h  = hm / 3, m = hm % 3;
    int n  = ((blockIdx.x & 15) << 4) + (threadIdx.x >> 4);
    int kc = (threadIdx.x & 15) << 4;
    const float* src = (m == 0 ? Wq : (m == 1 ? Wv : Wk)) + h * (ND * NL);
    f16x8 t0, t1;
    #pragma unroll
    for (int j = 0; j < 8; ++j) t0[j] = (f16)(src[(kc + j) * NL + n] * LOG2E);
    #pragma unroll
    for (int j = 0; j < 8; ++j) t1[j] = (f16)(src[(kc + 8 + j) * NL + n] * LOG2E);
    f16* dst = wh + ((size_t)(hm * 256 + n)) * 256 + kc;
    *(f16x8*)dst       = t0;
    *(f16x8*)(dst + 8) = t1;
}

// ---------------------------------------------------------------------------
// Prep: O (2048,256) f32 -> OT[n][k] f16 (k contiguous), scaled by LOG2E
// ---------------------------------------------------------------------------
__global__ __launch_bounds__(256) void ot_kernel(const float* __restrict__ O,
                                                 f16* __restrict__ OT) {
    int n = blockIdx.x;
    int t = threadIdx.x;
    f16x8 v;
    #pragma unroll
    for (int j = 0; j < 8; ++j) v[j] = (f16)(O[(size_t)(t * 8 + j) * 256 + n] * LOG2E);
    *(f16x8*)(OT + (size_t)n * 2048 + t * 8) = v;
}

// ---------------------------------------------------------------------------
// PKT[h][l][s] = LOG2E * P[s]·Wk[h][:,l]  (transposed; feeds k-sigmoid only)
// ---------------------------------------------------------------------------
__global__ __launch_bounds__(256) void pkt_kernel(const float* __restrict__ P,
                                                  const float* __restrict__ Wk,
                                                  float* __restrict__ PKT) {
    int h = blockIdx.x >> 6;
    int s = blockIdx.x & 63;
    int t = threadIdx.x;
    __shared__ float p_s[ND];
    p_s[t] = P[s * ND + t];
    __syncthreads();
    const float* wk = Wk + h * (ND * NL) + t;
    float acc = 0.f;
    #pragma unroll 8
    for (int d = 0; d < ND; ++d) acc = fmaf(p_s[d], wk[d * NL], acc);
    PKT[((size_t)h * NL + t) * NS + s] = acc * LOG2E;
}

// ---------------------------------------------------------------------------
// OK[h][b][l] = origin_b · (LOG2E*Wk[h][:,l])  as f16 MFMA GEMM
// ---------------------------------------------------------------------------
__global__ __launch_bounds__(256) void ok_gemm(const float* __restrict__ x,
                                               const f16*   __restrict__ wh,
                                               float* __restrict__ OK) {
    int mblk = blockIdx.x >> 4;          // 32
    int nblk = blockIdx.x & 15;          // 16
    int b0 = mblk * 64;
    int h  = nblk >> 1;
    int l0 = (nblk & 1) * 128;
    int t = threadIdx.x;
    int w = t >> 6, lane = t & 63, c = lane & 15, g = lane >> 4;

    __shared__ f16 Ao[64 * APAD];
    #pragma unroll
    for (int it = 0; it < 16; ++it) {
        int idx4 = it * 256 + t;
        int s = idx4 >> 6, kq = idx4 & 63;
        float4 v = *(const float4*)(x + (size_t)(b0 + s) * (NSEQ * ND) + kq * 4);
        *(f16x4*)(&Ao[s * APAD + kq * 4]) = (f16x4){(f16)v.x, (f16)v.y, (f16)v.z, (f16)v.w};
    }
    __syncthreads();

    f32x4 acc[4][2];
    #pragma unroll
    for (int mt = 0; mt < 4; ++mt)
        #pragma unroll
        for (int nt = 0; nt < 2; ++nt) acc[mt][nt] = (f32x4){0.f, 0.f, 0.f, 0.f};

    const f16* bb = wh + ((size_t)((h * 3 + 2) * 256 + l0 + w * 32 + c)) * 256;
    #pragma unroll 2
    for (int kk = 0; kk < 8; ++kk) {
        int k0 = kk * 32 + g * 8;
        f16x8 af[4];
        #pragma unroll
        for (int mt = 0; mt < 4; ++mt)
            af[mt] = *(const f16x8*)(&Ao[(mt * 16 + c) * APAD + k0]);
        #pragma unroll
        for (int nt = 0; nt < 2; ++nt) {
            f16x8 bf = *(const f16x8*)(bb + nt * 16 * 256 + k0);
            #pragma unroll
            for (int mt = 0; mt < 4; ++mt)
                acc[mt][nt] = __builtin_amdgcn_mfma_f32_16x16x32_f16(af[mt], bf, acc[mt][nt], 0, 0, 0);
        }
    }
    #pragma unroll
    for (int mt = 0; mt < 4; ++mt)
        #pragma unroll
        for (int nt = 0; nt < 2; ++nt)
            #pragma unroll
            for (int r = 0; r < 4; ++r)
                OK[((size_t)h * NB + b0 + mt * 16 + g * 4 + r) * NL + l0 + w * 32 + nt * 16 + c]
                    = acc[mt][nt][r];
}

// ---------------------------------------------------------------------------
// Main fused kernel: one block/batch; 512 threads = 8 waves, one head/wave.
// = R5's passing 681us structure (kk unroll 2, acc[4][2], VGPR 48, no spill)
// + AROW=288 (bank conflicts 33.55M -> 4.19M measured in R8)
// + setprio(1) around MFMA clusters (independent-wave regime, +4-7%).
// Full kk unroll is OFF: R8 proved it hits the 85-reg cap (VGPR 84 + spill).
// Occupancy is pinned ~46% by the unified register footprint; accepted.
// ---------------------------------------------------------------------------
__global__ __launch_bounds__(512, 3) void attn_mfma(
        const float* __restrict__ x,
        const f16*   __restrict__ wh,
        const float* __restrict__ W,
        const float* __restrict__ PKT,
        const float* __restrict__ OK,
        f16* __restrict__ res) {
    int b = blockIdx.x;
    int t = threadIdx.x;
    int w    = t >> 6;                   // 0..7 = head
    int lane = t & 63;
    int c = lane & 15;
    int g = lane >> 4;

    __shared__ f16 A[NS * AROW];         // 36864 B, swizzled + padded layout

    const float* xb = x + (size_t)b * (NSEQ * ND);

    // --- stage A (walk) once, swizzled ------------------------------------
    #pragma unroll
    for (int it = 0; it < 8; ++it) {
        int idx4 = it * 512 + t;
        int s  = idx4 >> 6;
        int kq = idx4 & 63;
        float4 v = *(const float4*)(xb + (1 + s) * ND + kq * 4);
        int kp = (kq * 4) ^ ((s & 7) << 3);
        *(f16x4*)(&A[s * AROW + kp]) = (f16x4){(f16)v.x, (f16)v.y, (f16)v.z, (f16)v.w};
    }
    __syncthreads();

    int swz = (c & 7) << 3;              // read-side swizzle (row&7 == c&7)
    int rot = b & 7;                     // chunk-phase rotation
    int h = w;                           // wave-private head

    // ---- pass 1: q-GEMM + edge, 8 chunks of 32 l-cols --------------------
    float part[4][4];                    // [mt][r] -> s = mt*16 + g*4 + r
    #pragma unroll
    for (int mt = 0; mt < 4; ++mt)
        #pragma unroll
        for (int r = 0; r < 4; ++r) part[mt][r] = 0.f;

    for (int ci = 0; ci < 8; ++ci) {
        int ch = (ci + rot) & 7;
        f32x4 acc[4][2];
        #pragma unroll
        for (int mt = 0; mt < 4; ++mt)
            #pragma unroll
            for (int nt = 0; nt < 2; ++nt) acc[mt][nt] = (f32x4){0.f, 0.f, 0.f, 0.f};

        const f16* bq = wh + ((size_t)((h * 3 + 0) * 256 + ch * 32 + c)) * 256;
        __builtin_amdgcn_s_setprio(1);
        #pragma unroll 2
        for (int kk = 0; kk < 8; ++kk) {
            int k0 = kk * 32 + g * 8;
            f16x8 af[4];
            #pragma unroll
            for (int mt = 0; mt < 4; ++mt)
                af[mt] = *(const f16x8*)(&A[(mt * 16 + c) * AROW + (k0 ^ swz)]);
            #pragma unroll
            for (int nt = 0; nt < 2; ++nt) {
                f16x8 bf = *(const f16x8*)(bq + nt * 16 * 256 + k0);
                #pragma unroll
                for (int mt = 0; mt < 4; ++mt)
                    acc[mt][nt] = __builtin_amdgcn_mfma_f32_16x16x32_f16(af[mt], bf, acc[mt][nt], 0, 0, 0);
            }
        }
        __builtin_amdgcn_s_setprio(0);
        // edge for this chunk (bias omitted: softmax-invariant shift)
        #pragma unroll
        for (int nt = 0; nt < 2; ++nt) {
            int l = ch * 32 + nt * 16 + c;
            float wl  = W[h * NL + l];
            float okv = OK[((size_t)h * NB + b) * NL + l];
            const float* pkcol = PKT + ((size_t)h * NL + l) * NS + g * 4;
            #pragma unroll
            for (int mt = 0; mt < 4; ++mt) {
                float4 pk4 = *(const float4*)(pkcol + mt * 16);
                float pks[4] = {pk4.x, pk4.y, pk4.z, pk4.w};
                #pragma unroll
                for (int r = 0; r < 4; ++r) {
                    float qs = sigmoid2_(acc[mt][nt][r]);
                    float ks = sigmoid2_(okv + pks[r]);
                    part[mt][r] = fmaf(cos_small_(ks * qs), wl, part[mt][r]);
                }
            }
        }
    }

    // ---- in-wave score reduction over c, then softmax over 64 s ----------
    #pragma unroll
    for (int mt = 0; mt < 4; ++mt)
        #pragma unroll
        for (int r = 0; r < 4; ++r) {
            float v = part[mt][r];
            v += __shfl_xor(v, 1, 64);
            v += __shfl_xor(v, 2, 64);
            v += __shfl_xor(v, 4, 64);
            v += __shfl_xor(v, 8, 64);
            part[mt][r] = v;             // score[s], uniform over c
        }
    float m = part[0][0];
    #pragma unroll
    for (int mt = 0; mt < 4; ++mt)
        #pragma unroll
        for (int r = 0; r < 4; ++r) m = fmaxf(m, part[mt][r]);
    m = fmaxf(m, __shfl_xor(m, 16, 64));
    m = fmaxf(m, __shfl_xor(m, 32, 64));
    float ssum = 0.f;
    #pragma unroll
    for (int mt = 0; mt < 4; ++mt)
        #pragma unroll
        for (int r = 0; r < 4; ++r) {
            float e = __expf(part[mt][r] - m);
            part[mt][r] = e;
            ssum += e;
        }
    ssum += __shfl_xor(ssum, 16, 64);
    ssum += __shfl_xor(ssum, 32, 64);
    float rinv = __builtin_amdgcn_rcpf(ssum);
    #pragma unroll
    for (int mt = 0; mt < 4; ++mt)
        #pragma unroll
        for (int r = 0; r < 4; ++r) part[mt][r] *= rinv;   // p_s

    // ---- pass 2: v-GEMM + weighted sigmoid sum, 8 chunks -----------------
    for (int ci = 0; ci < 8; ++ci) {
        int ch = (ci + rot) & 7;
        f32x4 acc[4][2];
        #pragma unroll
        for (int mt = 0; mt < 4; ++mt)
            #pragma unroll
            for (int nt = 0; nt < 2; ++nt) acc[mt][nt] = (f32x4){0.f, 0.f, 0.f, 0.f};

        const f16* bv = wh + ((size_t)((h * 3 + 1) * 256 + ch * 32 + c)) * 256;
        __builtin_amdgcn_s_setprio(1);
        #pragma unroll 2
        for (int kk = 0; kk < 8; ++kk) {
            int k0 = kk * 32 + g * 8;
            f16x8 af[4];
            #pragma unroll
            for (int mt = 0; mt < 4; ++mt)
                af[mt] = *(const f16x8*)(&A[(mt * 16 + c) * AROW + (k0 ^ swz)]);
            #pragma unroll
            for (int nt = 0; nt < 2; ++nt) {
                f16x8 bf = *(const f16x8*)(bv + nt * 16 * 256 + k0);
                #pragma unroll
                for (int mt = 0; mt < 4; ++mt)
                    acc[mt][nt] = __builtin_amdgcn_mfma_f32_16x16x32_f16(af[mt], bf, acc[mt][nt], 0, 0, 0);
            }
        }
        __builtin_amdgcn_s_setprio(0);
        #pragma unroll
        for (int nt = 0; nt < 2; ++nt) {
            float v = 0.f;
            #pragma unroll
            for (int mt = 0; mt < 4; ++mt)
                #pragma unroll
                for (int r = 0; r < 4; ++r)
                    v = fmaf(part[mt][r], sigmoid2_(acc[mt][nt][r]), v);
            v += __shfl_xor(v, 16, 64);
            v += __shfl_xor(v, 32, 64);
            if (g == 0)
                res[(size_t)b * 2048 + h * NL + ch * 32 + nt * 16 + c] = (f16)v;
        }
    }
}

// ---------------------------------------------------------------------------
// out GEMM: out[b][0:256] = sigmoid(res[b] @ O)  (f16 MFMA, K=2048)
// 32-row M tiles -> 128 blocks; OT pre-scaled by LOG2E -> sigmoid2_ epilogue
// ---------------------------------------------------------------------------
__global__ __launch_bounds__(256) void out_gemm(
        const float* __restrict__ x,
        const f16*   __restrict__ res,
        const f16*   __restrict__ OT,
        float* __restrict__ out) {
    int mblk = blockIdx.x >> 1;          // 64 tiles of 32 rows
    int nblk = blockIdx.x & 1;           // 128 cols each
    int b0 = mblk * 32;
    int t  = threadIdx.x;
    int w    = t >> 6;
    int lane = t & 63;
    int c = lane & 15;
    int g = lane >> 4;

    __shared__ f16 Ao[32 * APAD];

    f32x4 acc[2][2];
    #pragma unroll
    for (int mt = 0; mt < 2; ++mt)
        #pragma unroll
        for (int nt = 0; nt < 2; ++nt) acc[mt][nt] = (f32x4){0.f, 0.f, 0.f, 0.f};

    for (int chunk = 0; chunk < 8; ++chunk) {
        int kbase = chunk * 256;
        __syncthreads();
        #pragma unroll
        for (int it = 0; it < 4; ++it) {
            int id  = it * 256 + t;
            int row = id >> 5;
            int kc  = (id & 31) << 3;
            *(f16x8*)(&Ao[row * APAD + kc]) =
                *(const f16x8*)(res + (size_t)(b0 + row) * 2048 + kbase + kc);
        }
        __syncthreads();
        #pragma unroll
        for (int kk = 0; kk < 8; ++kk) {
            int k0 = kk * 32 + g * 8;
            f16x8 af[2];
            #pragma unroll
            for (int mt = 0; mt < 2; ++mt)
                af[mt] = *(const f16x8*)(&Ao[(mt * 16 + c) * APAD + k0]);
            #pragma unroll
            for (int nt = 0; nt < 2; ++nt) {
                f16x8 bf = *(const f16x8*)(OT + (size_t)(nblk * 128 + w * 32 + nt * 16 + c) * 2048 + kbase + k0);
                #pragma unroll
                for (int mt = 0; mt < 2; ++mt)
                    acc[mt][nt] = __builtin_amdgcn_mfma_f32_16x16x32_f16(af[mt], bf, acc[mt][nt], 0, 0, 0);
            }
        }
    }
    #pragma unroll
    for (int mt = 0; mt < 2; ++mt)
        #pragma unroll
        for (int nt = 0; nt < 2; ++nt)
            #pragma unroll
            for (int r = 0; r < 4; ++r) {
                int row = mt * 16 + g * 4 + r;
                int col = nblk * 128 + w * 32 + nt * 16 + c;
                out[(size_t)(b0 + row) * 512 + col] = sigmoid2_(acc[mt][nt][r]);
            }
    if (nblk == 1) {                     // origin passthrough for these 32 rows
        for (int r2 = 0; r2 < 32; ++r2)
            out[(size_t)(b0 + r2) * 512 + 256 + t] = x[(size_t)(b0 + r2) * (NSEQ * ND) + t];
    }
}

// ---------------------------------------------------------------------------
extern "C" void kernel_launch(void* const* d_in, const int* in_sizes, int n_in,
                              void* d_out, int out_size, void* d_ws, size_t ws_size,
                              hipStream_t stream) {
    const float* x    = (const float*)d_in[0];
    const float* Wq   = (const float*)d_in[1];
    const float* Wk   = (const float*)d_in[2];
    const float* Wv   = (const float*)d_in[3];
    const float* W    = (const float*)d_in[4];
    const float* O    = (const float*)d_in[5];
    const float* P    = (const float*)d_in[6];
    // d_in[7] = bias: unused — softmax is invariant to the bias*sum(W) shift
    float* out = (float*)d_out;

    // ws carve: wh 3MB | OT 1MB | PKT 512KB | OK 16MB | res 8MB  (~28.5MB)
    char* wsb = (char*)d_ws;
    f16*   wh  = (f16*)wsb;                       // 3*8*256*256 f16 = 3145728 B
    f16*   OT  = (f16*)(wsb + 3145728);           // 256*2048 f16   = 1048576 B
    float* PKT = (float*)(wsb + 4194304);         // 8*256*64 f32   = 524288 B
    float* OK  = (float*)(wsb + 4718592);         // 8*2048*256 f32 = 16777216 B
    f16*   res = (f16*)(wsb + 21495808);          // 2048*2048 f16  = 8388608 B

    wh_kernel<<<384, 256, 0, stream>>>(Wq, Wv, Wk, wh);
    ot_kernel<<<256, 256, 0, stream>>>(O, OT);
    pkt_kernel<<<NH * NS, 256, 0, stream>>>(P, Wk, PKT);
    ok_gemm<<<512, 256, 0, stream>>>(x, wh, OK);
    attn_mfma<<<NB, 512, 0, stream>>>(x, wh, W, PKT, OK, res);
    out_gemm<<<128, 256, 0, stream>>>(x, res, OT, out);
}